// Round 15
// baseline (587.737 us; speedup 1.0000x reference)
//
#include <hip/hip_runtime.h>
#include <hip/hip_bf16.h>
#include <cstdio>
#include <cstdint>

#define B_SZ    2
#define L_SEQ   1024
#define DMODEL  768
#define DINNER  1536
#define DSTATE  16
#define DTRANK  48
#define VOCAB   32000
#define BL      (B_SZ * L_SEQ)   // 2048
#define NCH     64               // scan chunks per sequence
#define CLEN    16               // timesteps per chunk (NCH*CLEN == L_SEQ)

typedef __bf16 bf16;
typedef __bf16 bf16x8 __attribute__((ext_vector_type(8)));
typedef __bf16 bf16x4 __attribute__((ext_vector_type(4)));
typedef float  f32x4  __attribute__((ext_vector_type(4)));

// ---------------- async global->LDS (16B/lane, wave-uniform base + lane*16) --
__device__ __forceinline__ void gload16(const void* g, void* l) {
  __builtin_amdgcn_global_load_lds(
      (const __attribute__((address_space(1))) void*)g,
      (__attribute__((address_space(3))) void*)l, 16, 0, 0);
}
__device__ __forceinline__ void memfence() { asm volatile("" ::: "memory"); }

// ---------------- embedding gather fused with hi/lo bf16 split --------------
__global__ void k_embed(const int* __restrict__ ids, const float* __restrict__ emb,
                        bf16* __restrict__ xh, bf16* __restrict__ xl) {
  const int row = blockIdx.x;
  const int id  = ids[row];
  const float4* s = (const float4*)(emb + (size_t)id * DMODEL);
  const int i = threadIdx.x;             // 192 threads = DMODEL/4
  const float4 v = s[i];
  bf16x4 hv, lv;
  hv[0] = (bf16)v.x; hv[1] = (bf16)v.y; hv[2] = (bf16)v.z; hv[3] = (bf16)v.w;
  lv[0] = (bf16)(v.x - (float)hv[0]); lv[1] = (bf16)(v.y - (float)hv[1]);
  lv[2] = (bf16)(v.z - (float)hv[2]); lv[3] = (bf16)(v.w - (float)hv[3]);
  *(bf16x4*)(xh + (size_t)row * DMODEL + i * 4) = hv;
  *(bf16x4*)(xl + (size_t)row * DMODEL + i * 4) = lv;
}

// ---------------- weight transpose + convert: W(K,N) f32 -> WT(N,K) bf16 ----
// Round-15: 64x64 tiles; 256B-coalesced reads, 128B-coalesced bf16 writes.
template<bool SPLIT>
__global__ __launch_bounds__(256) void k_tconv(
    const float* __restrict__ W, bf16* __restrict__ Th,
    bf16* __restrict__ Tl, int K, int N) {
  __shared__ float t[64][65];
  const int n0 = blockIdx.x * 64;
  const int k0 = blockIdx.y * 64;
  const int tx = threadIdx.x & 63;
  const int ty = threadIdx.x >> 6;   // 0..3
#pragma unroll
  for (int i = 0; i < 16; i++)
    t[ty + i * 4][tx] = W[(size_t)(k0 + ty + i * 4) * N + n0 + tx];
  __syncthreads();
#pragma unroll
  for (int i = 0; i < 16; i++) {
    const float v = t[tx][ty + i * 4];
    const bf16 hv = (bf16)v;
    Th[(size_t)(n0 + ty + i * 4) * K + k0 + tx] = hv;
    if constexpr (SPLIT)
      Tl[(size_t)(n0 + ty + i * 4) * K + k0 + tx] = (bf16)(v - (float)hv);
  }
}

// ---------------- transpose w_x (1536x80 f32 -> 80x1536 f32) ----------------
__global__ __launch_bounds__(256) void k_txw(const float* __restrict__ W,
                                             float* __restrict__ T) {
  __shared__ float t[16][17];
  const int k0 = blockIdx.x * 16;   // 96 blocks over K=1536
  const int c0 = blockIdx.y * 16;   // 5 blocks over 80
  const int tx = threadIdx.x & 15;
  const int ty = threadIdx.x >> 4;  // 0..15
  t[ty][tx] = W[(size_t)(k0 + ty) * 80 + c0 + tx];
  __syncthreads();
  T[(size_t)(c0 + ty) * DINNER + k0 + tx] = t[tx][ty];
}

// ---------------- bf16 MFMA GEMM, 128x128, A+B LDS 2-buf (round-8 form) -----
// stage(t+1) issued BEFORE compute(t); one vmcnt(0)+barrier per K-tile.
// SPLIT: AhBh + AlBh + AhBl. BF16OUT: write C as bf16 (fused cvt).
// fp32 epilogue coalesced via LDS transpose (full-row float4 runs).
template<bool SPLIT, bool BIAS, bool BF16OUT>
__global__ __launch_bounds__(256) void k_gemm(
    const bf16* __restrict__ Ah, const bf16* __restrict__ Al,
    const bf16* __restrict__ Bh, const bf16* __restrict__ Bl,
    const float* __restrict__ bias, float* __restrict__ C,
    int M, int N, int K) {
  __shared__ bf16 sAh[2][128 * 32];
  __shared__ bf16 sBh[2][128 * 32];
  __shared__ bf16 sAl[SPLIT ? 2 : 1][SPLIT ? 128 * 32 : 8];
  __shared__ bf16 sBl[SPLIT ? 2 : 1][SPLIT ? 128 * 32 : 8];

  const int tid  = threadIdx.x;
  const int lane = tid & 63;
  const int wave = tid >> 6;
  const int bm = blockIdx.y * 128;
  const int bn = blockIdx.x * 128;

  const int srow = tid >> 2;         // 0..63: staging row
  const int schk = (tid & 3) * 8;    // element offset in 32-wide K slab

  const bf16* gA0 = Ah + (size_t)(bm + srow) * K + schk;
  const bf16* gA1 = gA0 + (size_t)64 * K;
  const bf16* gB0 = Bh + (size_t)(bn + srow) * K + schk;
  const bf16* gB1 = gB0 + (size_t)64 * K;
  const bf16 *gA0l = nullptr, *gA1l = nullptr, *gB0l = nullptr, *gB1l = nullptr;
  if constexpr (SPLIT) {
    gA0l = Al + (size_t)(bm + srow) * K + schk;  gA1l = gA0l + (size_t)64 * K;
    gB0l = Bl + (size_t)(bn + srow) * K + schk;  gB1l = gB0l + (size_t)64 * K;
  }

  const int wmi = wave >> 1;         // 0..1 row-half index
  const int wm = wmi * 64;
  const int wn = (wave & 1) * 64;
  const int lr = lane & 15;
  const int kg = lane >> 4;

  f32x4 acc[4][4] = {};
  const int nt = K >> 5;

#define STG(t_, b_) do {                                                    \
    const size_t ko_ = (size_t)(t_) * 32;                                   \
    gload16(gA0 + ko_, &sAh[b_][tid * 8]);                                  \
    gload16(gA1 + ko_, &sAh[b_][2048 + tid * 8]);                           \
    gload16(gB0 + ko_, &sBh[b_][tid * 8]);                                  \
    gload16(gB1 + ko_, &sBh[b_][2048 + tid * 8]);                           \
    if constexpr (SPLIT) {                                                  \
      gload16(gA0l + ko_, &sAl[b_][tid * 8]);                               \
      gload16(gA1l + ko_, &sAl[b_][2048 + tid * 8]);                        \
      gload16(gB0l + ko_, &sBl[b_][tid * 8]);                               \
      gload16(gB1l + ko_, &sBl[b_][2048 + tid * 8]);                        \
    }                                                                       \
  } while (0)

  STG(0, 0);
  asm volatile("s_waitcnt vmcnt(0)" ::: "memory");
  __builtin_amdgcn_s_barrier();
  memfence();

  for (int t = 0; t < nt; ++t) {
    const int b = t & 1;
    if (t + 1 < nt) STG(t + 1, b ^ 1);   // overlap next-tile staging w/ compute

    bf16x8 af[4], bfv[4];
#pragma unroll
    for (int i = 0; i < 4; i++)
      af[i] = *(const bf16x8*)&sAh[b][(wm + i * 16 + lr) * 32 + kg * 8];
#pragma unroll
    for (int i = 0; i < 4; i++)
      bfv[i] = *(const bf16x8*)&sBh[b][(wn + i * 16 + lr) * 32 + kg * 8];

#pragma unroll
    for (int mi = 0; mi < 4; mi++)
#pragma unroll
      for (int ni = 0; ni < 4; ni++)
        acc[mi][ni] = __builtin_amdgcn_mfma_f32_16x16x32_bf16(
            af[mi], bfv[ni], acc[mi][ni], 0, 0, 0);

    if constexpr (SPLIT) {
      bf16x8 afl[4], bfl[4];
#pragma unroll
      for (int i = 0; i < 4; i++)
        afl[i] = *(const bf16x8*)&sAl[b][(wm + i * 16 + lr) * 32 + kg * 8];
#pragma unroll
      for (int i = 0; i < 4; i++)
        bfl[i] = *(const bf16x8*)&sBl[b][(wn + i * 16 + lr) * 32 + kg * 8];
#pragma unroll
      for (int mi = 0; mi < 4; mi++)
#pragma unroll
        for (int ni = 0; ni < 4; ni++) {
          acc[mi][ni] = __builtin_amdgcn_mfma_f32_16x16x32_bf16(
              afl[mi], bfv[ni], acc[mi][ni], 0, 0, 0);
          acc[mi][ni] = __builtin_amdgcn_mfma_f32_16x16x32_bf16(
              af[mi], bfl[ni], acc[mi][ni], 0, 0, 0);
        }
    }

    asm volatile("s_waitcnt vmcnt(0)" ::: "memory");  // next tile landed
    __builtin_amdgcn_s_barrier();                     // all waves done w/ buf b
    memfence();
  }
#undef STG

  if constexpr (!BF16OUT) {
    // coalesced epilogue: 8 chunks of 16 rows x 128 cols via LDS [16][136]
    float* T = (float*)sAh;   // 8704 B, fits in sAh (16 KB); loop is done w/ it
#pragma unroll
    for (int c = 0; c < 8; ++c) {
      __syncthreads();
      if ((c >> 2) == wmi) {
        const int mi = c & 3;
#pragma unroll
        for (int ni = 0; ni < 4; ++ni)
#pragma unroll
          for (int r = 0; r < 4; ++r)
            T[(kg * 4 + r) * 136 + wn + ni * 16 + lr] = acc[mi][ni][r];
      }
      __syncthreads();
#pragma unroll
      for (int q = 0; q < 2; ++q) {
        const int idx = q * 256 + tid;
        const int row = idx >> 5;          // 0..15
        const int c4  = idx & 31;          // 0..31 float4 cols
        float4 v = *(const float4*)&T[row * 136 + c4 * 4];
        if constexpr (BIAS) {
          const float4 b4 = *(const float4*)&bias[bn + c4 * 4];
          v.x += b4.x; v.y += b4.y; v.z += b4.z; v.w += b4.w;
        }
        *(float4*)&C[(size_t)(bm + c * 16 + row) * N + bn + c4 * 4] = v;
      }
    }
  } else {
    // bf16 output (out_proj, 3 MB) — scatter acceptable
#pragma unroll
    for (int mi = 0; mi < 4; mi++) {
#pragma unroll
      for (int ni = 0; ni < 4; ni++) {
        const int col = bn + wn + ni * 16 + lr;
        float bv = 0.f;
        if constexpr (BIAS) bv = bias[col];
#pragma unroll
        for (int r = 0; r < 4; r++) {
          const int row = bm + wm + mi * 16 + kg * 4 + r;
          ((bf16*)C)[(size_t)row * N + col] = (bf16)(acc[mi][ni][r] + bv);
        }
      }
    }
  }
}

// ========== 128x256 8-wave GEMM, 2-buf (lm_head) — round-14 verified ========
__global__ __launch_bounds__(512, 4) void k_gemm8(
    const bf16* __restrict__ A, const bf16* __restrict__ Bt,
    const float* __restrict__ bias, float* __restrict__ C,
    int M, int N, int K, int mblocks) {
  extern __shared__ bf16 lds[];   // staging: [2 bufs][A 4096 el | B 8192 el] = 49152 B
                                  // epilogue reuse: fp32 [32][264] (33792 B)

  // T1: bijective XCD swizzle (gridDim.x % 8 == 0 guaranteed by host)
  const int orig = (blockIdx.x & 7) * ((int)gridDim.x >> 3) + (blockIdx.x >> 3);
  const int bm = (orig % mblocks) * 128;
  const int bn = (orig / mblocks) * 256;

  const int tid  = threadIdx.x;
  const int lane = tid & 63;
  const int wave = tid >> 6;       // 0..7
  const int wm   = wave >> 2;      // 0..1 : M half (64 rows)
  const int wn   = wave & 3;       // 0..3 : N quarter (64 cols)
  const int lr   = lane & 15;
  const int kg   = lane >> 4;      // 0..3 : 16B k-slot
  const int sw   = (lr >> 1) & 3;  // read-side swizzle key

  // staging rows: A wave w -> rows [16w,16w+16); B wave w -> rows [32w,32w+32)
  const int srA = (wave << 4) + (lane >> 2);
  const int srB = (wave << 5) + (lane >> 2);
  const int ssA = (lane & 3) ^ ((srA >> 1) & 3);
  const int ssB = (lane & 3) ^ ((srB >> 1) & 3);   // same key for srB+16
  const size_t gAoff  = (size_t)(bm + srA) * K + ssA * 8;
  const size_t gBoff0 = (size_t)(bn + srB) * K + ssB * 8;
  const size_t gBoff1 = gBoff0 + (size_t)16 * K;

  // fragment read offsets within a buffer (elements, swizzled)
  const int aoff = (wm * 64 + lr) * 32 + ((kg ^ sw) << 3);
  const int boff = (wn * 64 + lr) * 32 + ((kg ^ sw) << 3);

  const int nt = K >> 5;   // 24

#define STAGE(ts_) do {                                                    \
    bf16* lb_ = lds + ((ts_) & 1) * 12288;                                 \
    const size_t ko_ = (size_t)(ts_) * 32;                                 \
    gload16(A  + gAoff  + ko_, lb_ + wave * 512);                          \
    gload16(Bt + gBoff0 + ko_, lb_ + 4096 + wave * 1024);                  \
    gload16(Bt + gBoff1 + ko_, lb_ + 4096 + wave * 1024 + 512);            \
  } while (0)

  f32x4 acc[4][4] = {};

  STAGE(0);
  asm volatile("s_waitcnt vmcnt(0)" ::: "memory");
  __builtin_amdgcn_s_barrier();
  memfence();

  for (int t = 0; t < nt; ++t) {
    if (t + 1 < nt) STAGE(t + 1);   // issue prefetch BEFORE ds_read/MFMA

    const bf16* lA = lds + (t & 1) * 12288;
    const bf16* lB = lA + 4096;

    bf16x8 bfr[4], afr[4];
#pragma unroll
    for (int j = 0; j < 4; j++) bfr[j] = *(const bf16x8*)(lB + boff + j * 512);
#pragma unroll
    for (int i = 0; i < 4; i++) afr[i] = *(const bf16x8*)(lA + aoff + i * 512);

    __builtin_amdgcn_s_setprio(1);
#pragma unroll
    for (int i = 0; i < 4; i++)
#pragma unroll
      for (int j = 0; j < 4; j++)
        acc[i][j] = __builtin_amdgcn_mfma_f32_16x16x32_bf16(afr[i], bfr[j], acc[i][j], 0, 0, 0);
    __builtin_amdgcn_s_setprio(0);

    asm volatile("s_waitcnt vmcnt(0)" ::: "memory");  // tile t+1 landed
    __builtin_amdgcn_s_barrier();
    memfence();
  }
#undef STAGE

  // ---- coalesced epilogue (4 chunks of 32 rows via LDS [32][264]) ----
  {
    float* T = (float*)lds;
    const int CS = 264;
#pragma unroll
    for (int c = 0; c < 4; ++c) {
      __syncthreads();                 // prev chunk consumed / staging LDS free
      if ((c >> 1) == wm) {
#pragma unroll
        for (int s = 0; s < 2; ++s) {
          const int il = 2 * (c & 1) + s;
#pragma unroll
          for (int j = 0; j < 4; ++j)
#pragma unroll
            for (int r = 0; r < 4; ++r)
              T[(s * 16 + kg * 4 + r) * CS + wn * 64 + j * 16 + lr] = acc[il][j][r];
        }
      }
      __syncthreads();                 // full lgkmcnt drain: writes visible
#pragma unroll
      for (int q = 0; q < 4; ++q) {
        const int idx = q * 512 + tid;
        const int row = idx >> 6;        // 0..31
        const int c4  = idx & 63;        // 0..63 float4 cols (256 cols)
        const float4 b4 = *(const float4*)&bias[bn + c4 * 4];
        float4 v = *(const float4*)&T[row * CS + c4 * 4];
        v.x += b4.x; v.y += b4.y; v.z += b4.z; v.w += b4.w;
        *(float4*)&C[(size_t)(bm + c * 32 + row) * N + bn + c4 * 4] = v;
      }
    }
  }
}

// ---------------- depthwise causal conv (D_CONV=4) + silu -------------------
__global__ void k_conv(const float* __restrict__ xz, const float* __restrict__ cw,
                       const float* __restrict__ cb, float* __restrict__ xa) {
  const int bl = blockIdx.x;
  const int l  = bl & (L_SEQ - 1);
  for (int d = threadIdx.x; d < DINNER; d += blockDim.x) {
    float acc = cb[d];
#pragma unroll
    for (int k = 0; k < 4; k++) {
      const int ll = l + k - 3;
      if (ll >= 0)
        acc = fmaf(xz[(size_t)(bl + k - 3) * (2 * DINNER) + d], cw[d * 4 + k], acc);
    }
    xa[(size_t)bl * DINNER + d] = acc / (1.f + __expf(-acc));
  }
}

// ---------------- x_proj (round-15): wt(80,1536) + float4 reg-tiled ---------
// dbl(2048,80) = xa(2048,1536) @ w_x; thread computes 2 cols of 1 row.
// Accumulation order identical to scalar version (k ascending) -> bit-exact.
__global__ __launch_bounds__(256) void k_xproj(
    const float* __restrict__ xa, const float* __restrict__ wt,
    float* __restrict__ dbl) {
  const int gid = blockIdx.x * 256 + threadIdx.x;   // 81920 = 2048 x 40
  const int r  = gid / 40;
  const int c0 = (gid % 40) * 2;
  const float4* xr = (const float4*)(xa + (size_t)r * DINNER);
  const float4* w0 = (const float4*)(wt + (size_t)c0 * DINNER);
  const float4* w1 = (const float4*)(wt + (size_t)(c0 + 1) * DINNER);
  float a0 = 0.f, a1 = 0.f;
  for (int k = 0; k < DINNER / 4; k++) {
    const float4 x = xr[k];
    const float4 u = w0[k];
    const float4 v = w1[k];
    a0 = fmaf(x.x, u.x, a0); a0 = fmaf(x.y, u.y, a0);
    a0 = fmaf(x.z, u.z, a0); a0 = fmaf(x.w, u.w, a0);
    a1 = fmaf(x.x, v.x, a1); a1 = fmaf(x.y, v.y, a1);
    a1 = fmaf(x.z, v.z, a1); a1 = fmaf(x.w, v.w, a1);
  }
  dbl[(size_t)r * 80 + c0]     = a0;
  dbl[(size_t)r * 80 + c0 + 1] = a1;
}

// ---------------- dt_proj + softplus, 8 rows/block (w_dt L2 reuse x8) -------
__global__ __launch_bounds__(256) void k_dtproj(
    const float* __restrict__ dbl, const float* __restrict__ w,
    const float* __restrict__ bvec, float* __restrict__ dt) {
  const int r0 = blockIdx.x * 8;
  const int tid = threadIdx.x;
  __shared__ float ds[8][DTRANK];
  for (int i = tid; i < 8 * DTRANK; i += 256)
    ds[i / DTRANK][i % DTRANK] = dbl[(size_t)(r0 + i / DTRANK) * 80 + i % DTRANK];
  __syncthreads();
  for (int c = tid; c < DINNER; c += 256) {
    const float bvc = bvec[c];
    float acc[8];
#pragma unroll
    for (int j = 0; j < 8; j++) acc[j] = bvc;
    for (int k = 0; k < DTRANK; k++) {
      const float wv = w[(size_t)k * DINNER + c];
#pragma unroll
      for (int j = 0; j < 8; j++) acc[j] = fmaf(ds[j][k], wv, acc[j]);
    }
#pragma unroll
    for (int j = 0; j < 8; j++) {
      const float a = acc[j];
      dt[(size_t)(r0 + j) * DINNER + c] = (a > 20.f) ? a : log1pf(expf(a));
    }
  }
}

// ======================= chunk-parallel selective scan =======================
__global__ __launch_bounds__(256) void k_scan1(
    const float* __restrict__ dt, const float* __restrict__ dbl,
    const float* __restrict__ xa, const float* __restrict__ a_log,
    float* __restrict__ P, float* __restrict__ S) {
  const int tid = threadIdx.x;
  const int d = blockIdx.x * 256 + tid;
  const int c = blockIdx.y;
  const int b = blockIdx.z;
  __shared__ float sB[CLEN][DSTATE];
  {
    const int j = tid >> 4, n = tid & 15;
    sB[j][n] = dbl[(size_t)(b * L_SEQ + c * CLEN + j) * 80 + DTRANK + n];
  }
  __syncthreads();
  float a[16];
#pragma unroll
  for (int q = 0; q < 4; q++) {
    const float4 v = *(const float4*)&a_log[d * DSTATE + q * 4];
    a[q*4+0] = -expf(v.x); a[q*4+1] = -expf(v.y);
    a[q*4+2] = -expf(v.z); a[q*4+3] = -expf(v.w);
  }
  float h[16] = {}, p[16];
#pragma unroll
  for (int n = 0; n < 16; n++) p[n] = 1.f;
  const size_t rowb = (size_t)(b * L_SEQ + c * CLEN);
#pragma unroll 4
  for (int j = 0; j < CLEN; j++) {
    const size_t row = rowb + j;
    const float dtv = dt[row * DINNER + d];
    const float xav = xa[row * DINNER + d];
    const float du  = dtv * xav;
#pragma unroll
    for (int n = 0; n < 16; n++) {
      const float dA = __expf(dtv * a[n]);
      h[n] = fmaf(dA, h[n], du * sB[j][n]);
      p[n] *= dA;
    }
  }
  const size_t base = (((size_t)c * B_SZ + b) * DINNER + d) * DSTATE;
#pragma unroll
  for (int q = 0; q < 4; q++) {
    *(float4*)&P[base + q * 4] = make_float4(p[q*4], p[q*4+1], p[q*4+2], p[q*4+3]);
    *(float4*)&S[base + q * 4] = make_float4(h[q*4], h[q*4+1], h[q*4+2], h[q*4+3]);
  }
}

__global__ __launch_bounds__(256) void k_scan2(
    const float* __restrict__ P, const float* __restrict__ S,
    float* __restrict__ Hin) {
  const int gid = blockIdx.x * 256 + threadIdx.x;   // (b*DINNER+d)*16+n
  const int STRIDE = B_SZ * DINNER * DSTATE;        // 49152
  float h = 0.f;
#pragma unroll 4
  for (int c = 0; c < NCH; c++) {
    Hin[(size_t)c * STRIDE + gid] = h;
    h = fmaf(P[(size_t)c * STRIDE + gid], h, S[(size_t)c * STRIDE + gid]);
  }
}

// scan3: re-scan with true h0, fused epilogue, writes hi/lo bf16 split of
// ycmb directly (feeds out_proj A operand)
__global__ __launch_bounds__(256) void k_scan3(
    const float* __restrict__ dt, const float* __restrict__ dbl,
    const float* __restrict__ xa, const float* __restrict__ a_log,
    const float* __restrict__ dvec, const float* __restrict__ xz,
    const float* __restrict__ Hin, bf16* __restrict__ ych,
    bf16* __restrict__ ycl) {
  const int tid = threadIdx.x;
  const int d = blockIdx.x * 256 + tid;
  const int c = blockIdx.y;
  const int b = blockIdx.z;
  __shared__ float sB[CLEN][DSTATE];
  __shared__ float sC[CLEN][DSTATE];
  {
    const int j = tid >> 4, n = tid & 15;
    const size_t r80 = (size_t)(b * L_SEQ + c * CLEN + j) * 80;
    sB[j][n] = dbl[r80 + DTRANK + n];
    sC[j][n] = dbl[r80 + DTRANK + DSTATE + n];
  }
  __syncthreads();
  float a[16];
#pragma unroll
  for (int q = 0; q < 4; q++) {
    const float4 v = *(const float4*)&a_log[d * DSTATE + q * 4];
    a[q*4+0] = -expf(v.x); a[q*4+1] = -expf(v.y);
    a[q*4+2] = -expf(v.z); a[q*4+3] = -expf(v.w);
  }
  float h[16];
  const size_t base = (((size_t)c * B_SZ + b) * DINNER + d) * DSTATE;
#pragma unroll
  for (int q = 0; q < 4; q++) {
    const float4 v = *(const float4*)&Hin[base + q * 4];
    h[q*4+0] = v.x; h[q*4+1] = v.y; h[q*4+2] = v.z; h[q*4+3] = v.w;
  }
  const float Dv = dvec[d];
  const size_t rowb = (size_t)(b * L_SEQ + c * CLEN);
#pragma unroll 4
  for (int j = 0; j < CLEN; j++) {
    const size_t row = rowb + j;
    const float dtv = dt[row * DINNER + d];
    const float xav = xa[row * DINNER + d];
    const float du  = dtv * xav;
    float y = 0.f;
#pragma unroll
    for (int n = 0; n < 16; n++) {
      const float dA = __expf(dtv * a[n]);
      h[n] = fmaf(dA, h[n], du * sB[j][n]);
      y = fmaf(h[n], sC[j][n], y);
    }
    const float z  = xz[row * (2 * DINNER) + DINNER + d];
    const float sz = z / (1.f + __expf(-z));
    const float val = fmaf(xav, Dv, y) * sz;
    const bf16 hv = (bf16)val;
    ych[row * DINNER + d] = hv;
    ycl[row * DINNER + d] = (bf16)(val - (float)hv);
  }
}

// ============================================================================
extern "C" void kernel_launch(void* const* d_in, const int* in_sizes, int n_in,
                              void* d_out, int out_size, void* d_ws, size_t ws_size,
                              hipStream_t stream) {
  const int*   ids   = (const int*)d_in[0];
  const float* emb   = (const float*)d_in[1];
  const float* w_in  = (const float*)d_in[2];   // 768 x 3072
  const float* cw    = (const float*)d_in[3];   // 1536 x 4
  const float* cb    = (const float*)d_in[4];
  const float* w_x   = (const float*)d_in[5];   // 1536 x 80
  const float* w_dt  = (const float*)d_in[6];   // 48 x 1536
  const float* b_dt  = (const float*)d_in[7];
  const float* a_log = (const float*)d_in[8];   // 1536 x 16
  const float* dvec  = (const float*)d_in[9];
  const float* w_out = (const float*)d_in[10];  // 1536 x 768
  const float* w_lm  = (const float*)d_in[11];  // 768 x 32000
  const float* b_lm  = (const float*)d_in[12];
  float* out = (float*)d_out;

  char* ws = (char*)d_ws;
  size_t off = 0;
  auto alloc = [&](size_t bytes) {
    void* p = ws + off;
    off = (off + bytes + 255) & ~(size_t)255;
    return p;
  };
  float* xw    = (float*)alloc((size_t)BL * DMODEL * 4);   // hosts wxt (492 KB)
  float* xz    = (float*)alloc((size_t)BL * 2 * DINNER * 4);
  float* xa    = (float*)alloc((size_t)BL * DINNER * 4);
  float* dbl   = (float*)alloc((size_t)BL * 80 * 4);
  float* dt    = (float*)alloc((size_t)BL * DINNER * 4);
  float* ycmb  = (float*)alloc((size_t)BL * DINNER * 4);   // (spare)
  float* yo    = (float*)alloc((size_t)BL * DMODEL * 4);   // (spare)
  bf16* xwh    = (bf16*)alloc((size_t)BL * DMODEL * 2);
  bf16* xwl    = (bf16*)alloc((size_t)BL * DMODEL * 2);
  bf16* wtinh  = (bf16*)alloc((size_t)3072 * DMODEL * 2);
  bf16* wtinl  = (bf16*)alloc((size_t)3072 * DMODEL * 2);
  bf16* ych    = (bf16*)alloc((size_t)BL * DINNER * 2);
  bf16* ycl    = (bf16*)alloc((size_t)BL * DINNER * 2);
  bf16* wtoh   = (bf16*)alloc((size_t)DMODEL * DINNER * 2);
  bf16* wtol   = (bf16*)alloc((size_t)DMODEL * DINNER * 2);
  bf16* yob    = (bf16*)alloc((size_t)BL * DMODEL * 2);
  bf16* wtlm   = (bf16*)alloc((size_t)VOCAB * DMODEL * 2);
  (void)ycmb; (void)yo;
  if (off > ws_size) {
    fprintf(stderr, "kernel_launch: ws too small (need %zu, have %zu)\n", off, ws_size);
    return;
  }

  // Aliased scratch (dead-lifetime regions):
  //  P -> xwh+xwl (dead after in_proj GEMM); S -> ych+ycl (scan3 overwrites
  //  AFTER scan2 consumed S); Hin -> wtlm (consumed by scan3, then tconv_lm
  //  overwrites); wxt -> xw (region otherwise unused).
  float* Pbuf = (float*)xwh;
  float* Sbuf = (float*)ych;
  float* Hin  = (float*)wtlm;
  float* wxt  = xw;   // 80 x 1536 f32

  // 48 KB dynamic LDS for k_gemm8 (staging 2 x 24576 B; epilogue 33792 B)
  (void)hipFuncSetAttribute((const void*)k_gemm8,
                            hipFuncAttributeMaxDynamicSharedMemorySize, 49152);

  // 1. embed fused with hi/lo split; transpose w_x for fast xproj
  k_embed<<<BL, DMODEL / 4, 0, stream>>>(ids, emb, xwh, xwl);
  k_txw<<<dim3(DINNER / 16, 80 / 16), 256, 0, stream>>>(w_x, wxt);
  // 2. transpose-convert in_proj weight (64x64 tiles)
  k_tconv<true><<<dim3(3072 / 64, DMODEL / 64), 256, 0, stream>>>(w_in, wtinh, wtinl, DMODEL, 3072);
  // 3. in_proj GEMM (split, fp32-exact-ish): xz = xw @ w_in
  k_gemm<true, false, false><<<dim3(3072 / 128, BL / 128), 256, 0, stream>>>(
      xwh, xwl, wtinh, wtinl, nullptr, xz, BL, 3072, DMODEL);
  // 4. conv + silu
  k_conv<<<BL, 256, 0, stream>>>(xz, cw, cb, xa);
  // 5. x_proj (fp32, float4 reg-tiled)
  k_xproj<<<(BL * 40) / 256, 256, 0, stream>>>(xa, wxt, dbl);
  // 6. dt_proj + softplus (fp32, 8 rows/block)
  k_dtproj<<<BL / 8, 256, 0, stream>>>(dbl, w_dt, b_dt, dt);
  // 7. chunk-parallel scan; scan3 writes split bf16 directly
  k_scan1<<<dim3(DINNER / 256, NCH, B_SZ), 256, 0, stream>>>(dt, dbl, xa, a_log, Pbuf, Sbuf);
  k_scan2<<<(B_SZ * DINNER * DSTATE) / 256, 256, 0, stream>>>(Pbuf, Sbuf, Hin);
  k_scan3<<<dim3(DINNER / 256, NCH, B_SZ), 256, 0, stream>>>(dt, dbl, xa, a_log, dvec, xz, Hin, ych, ycl);
  // 8. out_proj GEMM (split), bf16 output fused (yob)
  k_tconv<true><<<dim3(DMODEL / 64, DINNER / 64), 256, 0, stream>>>(w_out, wtoh, wtol, DINNER, DMODEL);
  k_gemm<true, false, true><<<dim3(DMODEL / 128, BL / 128), 256, 0, stream>>>(
      ych, ycl, wtoh, wtol, nullptr, (float*)yob, BL, DMODEL, DINNER);
  // 9. lm_head GEMM: 128x256 8-wave 2-buf, coalesced fp32 epilogue
  k_tconv<false><<<dim3(VOCAB / 64, DMODEL / 64), 256, 0, stream>>>(w_lm, wtlm, nullptr, DMODEL, VOCAB);
  {
    const int mb = BL / 128;                 // 16
    const int nb = VOCAB / 256;              // 125
    k_gemm8<<<mb * nb, 512, 49152, stream>>>(yob, wtlm, b_lm, out,
                                             BL, VOCAB, DMODEL, mb);
  }
}

// Round 16
// 450.281 us; speedup vs baseline: 1.3053x; 1.3053x over previous
//
#include <hip/hip_runtime.h>
#include <hip/hip_bf16.h>
#include <cstdio>
#include <cstdint>

#define B_SZ    2
#define L_SEQ   1024
#define DMODEL  768
#define DINNER  1536
#define DSTATE  16
#define DTRANK  48
#define VOCAB   32000
#define BL      (B_SZ * L_SEQ)   // 2048
#define NCH     64               // scan chunks per sequence
#define CLEN    16               // timesteps per chunk (NCH*CLEN == L_SEQ)

typedef __bf16 bf16;
typedef __bf16 bf16x8 __attribute__((ext_vector_type(8)));
typedef __bf16 bf16x4 __attribute__((ext_vector_type(4)));
typedef float  f32x4  __attribute__((ext_vector_type(4)));

// ---------------- async global->LDS (16B/lane, wave-uniform base + lane*16) --
__device__ __forceinline__ void gload16(const void* g, void* l) {
  __builtin_amdgcn_global_load_lds(
      (const __attribute__((address_space(1))) void*)g,
      (__attribute__((address_space(3))) void*)l, 16, 0, 0);
}
__device__ __forceinline__ void memfence() { asm volatile("" ::: "memory"); }

// ---------------- embedding gather fused with hi/lo bf16 split --------------
__global__ void k_embed(const int* __restrict__ ids, const float* __restrict__ emb,
                        bf16* __restrict__ xh, bf16* __restrict__ xl) {
  const int row = blockIdx.x;
  const int id  = ids[row];
  const float4* s = (const float4*)(emb + (size_t)id * DMODEL);
  const int i = threadIdx.x;             // 192 threads = DMODEL/4
  const float4 v = s[i];
  bf16x4 hv, lv;
  hv[0] = (bf16)v.x; hv[1] = (bf16)v.y; hv[2] = (bf16)v.z; hv[3] = (bf16)v.w;
  lv[0] = (bf16)(v.x - (float)hv[0]); lv[1] = (bf16)(v.y - (float)hv[1]);
  lv[2] = (bf16)(v.z - (float)hv[2]); lv[3] = (bf16)(v.w - (float)hv[3]);
  *(bf16x4*)(xh + (size_t)row * DMODEL + i * 4) = hv;
  *(bf16x4*)(xl + (size_t)row * DMODEL + i * 4) = lv;
}

// ---------------- weight transpose + convert: W(K,N) f32 -> WT(N,K) bf16 ----
// 64x64 tiles; 256B-coalesced reads, 128B-coalesced bf16 writes.
template<bool SPLIT>
__global__ __launch_bounds__(256) void k_tconv(
    const float* __restrict__ W, bf16* __restrict__ Th,
    bf16* __restrict__ Tl, int K, int N) {
  __shared__ float t[64][65];
  const int n0 = blockIdx.x * 64;
  const int k0 = blockIdx.y * 64;
  const int tx = threadIdx.x & 63;
  const int ty = threadIdx.x >> 6;   // 0..3
#pragma unroll
  for (int i = 0; i < 16; i++)
    t[ty + i * 4][tx] = W[(size_t)(k0 + ty + i * 4) * N + n0 + tx];
  __syncthreads();
#pragma unroll
  for (int i = 0; i < 16; i++) {
    const float v = t[tx][ty + i * 4];
    const bf16 hv = (bf16)v;
    Th[(size_t)(n0 + ty + i * 4) * K + k0 + tx] = hv;
    if constexpr (SPLIT)
      Tl[(size_t)(n0 + ty + i * 4) * K + k0 + tx] = (bf16)(v - (float)hv);
  }
}

// ---------------- transpose w_x (1536x80 f32 -> 80x1536 f32) ----------------
__global__ __launch_bounds__(256) void k_txw(const float* __restrict__ W,
                                             float* __restrict__ T) {
  __shared__ float t[16][17];
  const int k0 = blockIdx.x * 16;   // 96 blocks over K=1536
  const int c0 = blockIdx.y * 16;   // 5 blocks over 80
  const int tx = threadIdx.x & 15;
  const int ty = threadIdx.x >> 4;  // 0..15
  t[ty][tx] = W[(size_t)(k0 + ty) * 80 + c0 + tx];
  __syncthreads();
  T[(size_t)(c0 + ty) * DINNER + k0 + tx] = t[tx][ty];
}

// ---------------- bf16 MFMA GEMM, 128x128, A+B LDS 2-buf (round-8 form) -----
// stage(t+1) issued BEFORE compute(t); one vmcnt(0)+barrier per K-tile.
// SPLIT: AhBh + AlBh + AhBl. BF16OUT: write C as bf16 (fused cvt).
// fp32 epilogue coalesced via LDS transpose (full-row float4 runs).
template<bool SPLIT, bool BIAS, bool BF16OUT>
__global__ __launch_bounds__(256) void k_gemm(
    const bf16* __restrict__ Ah, const bf16* __restrict__ Al,
    const bf16* __restrict__ Bh, const bf16* __restrict__ Bl,
    const float* __restrict__ bias, float* __restrict__ C,
    int M, int N, int K) {
  __shared__ bf16 sAh[2][128 * 32];
  __shared__ bf16 sBh[2][128 * 32];
  __shared__ bf16 sAl[SPLIT ? 2 : 1][SPLIT ? 128 * 32 : 8];
  __shared__ bf16 sBl[SPLIT ? 2 : 1][SPLIT ? 128 * 32 : 8];

  const int tid  = threadIdx.x;
  const int lane = tid & 63;
  const int wave = tid >> 6;
  const int bm = blockIdx.y * 128;
  const int bn = blockIdx.x * 128;

  const int srow = tid >> 2;         // 0..63: staging row
  const int schk = (tid & 3) * 8;    // element offset in 32-wide K slab

  const bf16* gA0 = Ah + (size_t)(bm + srow) * K + schk;
  const bf16* gA1 = gA0 + (size_t)64 * K;
  const bf16* gB0 = Bh + (size_t)(bn + srow) * K + schk;
  const bf16* gB1 = gB0 + (size_t)64 * K;
  const bf16 *gA0l = nullptr, *gA1l = nullptr, *gB0l = nullptr, *gB1l = nullptr;
  if constexpr (SPLIT) {
    gA0l = Al + (size_t)(bm + srow) * K + schk;  gA1l = gA0l + (size_t)64 * K;
    gB0l = Bl + (size_t)(bn + srow) * K + schk;  gB1l = gB0l + (size_t)64 * K;
  }

  const int wmi = wave >> 1;         // 0..1 row-half index
  const int wm = wmi * 64;
  const int wn = (wave & 1) * 64;
  const int lr = lane & 15;
  const int kg = lane >> 4;

  f32x4 acc[4][4] = {};
  const int nt = K >> 5;

#define STG(t_, b_) do {                                                    \
    const size_t ko_ = (size_t)(t_) * 32;                                   \
    gload16(gA0 + ko_, &sAh[b_][tid * 8]);                                  \
    gload16(gA1 + ko_, &sAh[b_][2048 + tid * 8]);                           \
    gload16(gB0 + ko_, &sBh[b_][tid * 8]);                                  \
    gload16(gB1 + ko_, &sBh[b_][2048 + tid * 8]);                           \
    if constexpr (SPLIT) {                                                  \
      gload16(gA0l + ko_, &sAl[b_][tid * 8]);                               \
      gload16(gA1l + ko_, &sAl[b_][2048 + tid * 8]);                        \
      gload16(gB0l + ko_, &sBl[b_][tid * 8]);                               \
      gload16(gB1l + ko_, &sBl[b_][2048 + tid * 8]);                        \
    }                                                                       \
  } while (0)

  STG(0, 0);
  asm volatile("s_waitcnt vmcnt(0)" ::: "memory");
  __builtin_amdgcn_s_barrier();
  memfence();

  for (int t = 0; t < nt; ++t) {
    const int b = t & 1;
    if (t + 1 < nt) STG(t + 1, b ^ 1);   // overlap next-tile staging w/ compute

    bf16x8 af[4], bfv[4];
#pragma unroll
    for (int i = 0; i < 4; i++)
      af[i] = *(const bf16x8*)&sAh[b][(wm + i * 16 + lr) * 32 + kg * 8];
#pragma unroll
    for (int i = 0; i < 4; i++)
      bfv[i] = *(const bf16x8*)&sBh[b][(wn + i * 16 + lr) * 32 + kg * 8];

#pragma unroll
    for (int mi = 0; mi < 4; mi++)
#pragma unroll
      for (int ni = 0; ni < 4; ni++)
        acc[mi][ni] = __builtin_amdgcn_mfma_f32_16x16x32_bf16(
            af[mi], bfv[ni], acc[mi][ni], 0, 0, 0);

    if constexpr (SPLIT) {
      bf16x8 afl[4], bfl[4];
#pragma unroll
      for (int i = 0; i < 4; i++)
        afl[i] = *(const bf16x8*)&sAl[b][(wm + i * 16 + lr) * 32 + kg * 8];
#pragma unroll
      for (int i = 0; i < 4; i++)
        bfl[i] = *(const bf16x8*)&sBl[b][(wn + i * 16 + lr) * 32 + kg * 8];
#pragma unroll
      for (int mi = 0; mi < 4; mi++)
#pragma unroll
        for (int ni = 0; ni < 4; ni++) {
          acc[mi][ni] = __builtin_amdgcn_mfma_f32_16x16x32_bf16(
              afl[mi], bfv[ni], acc[mi][ni], 0, 0, 0);
          acc[mi][ni] = __builtin_amdgcn_mfma_f32_16x16x32_bf16(
              af[mi], bfl[ni], acc[mi][ni], 0, 0, 0);
        }
    }

    asm volatile("s_waitcnt vmcnt(0)" ::: "memory");  // next tile landed
    __builtin_amdgcn_s_barrier();                     // all waves done w/ buf b
    memfence();
  }
#undef STG

  if constexpr (!BF16OUT) {
    // coalesced epilogue: 8 chunks of 16 rows x 128 cols via LDS [16][136]
    float* T = (float*)sAh;   // 8704 B, fits in sAh (16 KB); loop is done w/ it
#pragma unroll
    for (int c = 0; c < 8; ++c) {
      __syncthreads();
      if ((c >> 2) == wmi) {
        const int mi = c & 3;
#pragma unroll
        for (int ni = 0; ni < 4; ++ni)
#pragma unroll
          for (int r = 0; r < 4; ++r)
            T[(kg * 4 + r) * 136 + wn + ni * 16 + lr] = acc[mi][ni][r];
      }
      __syncthreads();
#pragma unroll
      for (int q = 0; q < 2; ++q) {
        const int idx = q * 256 + tid;
        const int row = idx >> 5;          // 0..15
        const int c4  = idx & 31;          // 0..31 float4 cols
        float4 v = *(const float4*)&T[row * 136 + c4 * 4];
        if constexpr (BIAS) {
          const float4 b4 = *(const float4*)&bias[bn + c4 * 4];
          v.x += b4.x; v.y += b4.y; v.z += b4.z; v.w += b4.w;
        }
        *(float4*)&C[(size_t)(bm + c * 16 + row) * N + bn + c4 * 4] = v;
      }
    }
  } else {
    // bf16 output (out_proj, 3 MB) — scatter acceptable
#pragma unroll
    for (int mi = 0; mi < 4; mi++) {
#pragma unroll
      for (int ni = 0; ni < 4; ni++) {
        const int col = bn + wn + ni * 16 + lr;
        float bv = 0.f;
        if constexpr (BIAS) bv = bias[col];
#pragma unroll
        for (int r = 0; r < 4; r++) {
          const int row = bm + wm + mi * 16 + kg * 4 + r;
          ((bf16*)C)[(size_t)row * N + col] = (bf16)(acc[mi][ni][r] + bv);
        }
      }
    }
  }
}

// ========== 128x256 8-wave GEMM, 2-buf (lm_head) — round-14 verified ========
__global__ __launch_bounds__(512, 4) void k_gemm8(
    const bf16* __restrict__ A, const bf16* __restrict__ Bt,
    const float* __restrict__ bias, float* __restrict__ C,
    int M, int N, int K, int mblocks) {
  extern __shared__ bf16 lds[];   // staging: [2 bufs][A 4096 el | B 8192 el] = 49152 B
                                  // epilogue reuse: fp32 [32][264] (33792 B)

  // T1: bijective XCD swizzle (gridDim.x % 8 == 0 guaranteed by host)
  const int orig = (blockIdx.x & 7) * ((int)gridDim.x >> 3) + (blockIdx.x >> 3);
  const int bm = (orig % mblocks) * 128;
  const int bn = (orig / mblocks) * 256;

  const int tid  = threadIdx.x;
  const int lane = tid & 63;
  const int wave = tid >> 6;       // 0..7
  const int wm   = wave >> 2;      // 0..1 : M half (64 rows)
  const int wn   = wave & 3;       // 0..3 : N quarter (64 cols)
  const int lr   = lane & 15;
  const int kg   = lane >> 4;      // 0..3 : 16B k-slot
  const int sw   = (lr >> 1) & 3;  // read-side swizzle key

  // staging rows: A wave w -> rows [16w,16w+16); B wave w -> rows [32w,32w+32)
  const int srA = (wave << 4) + (lane >> 2);
  const int srB = (wave << 5) + (lane >> 2);
  const int ssA = (lane & 3) ^ ((srA >> 1) & 3);
  const int ssB = (lane & 3) ^ ((srB >> 1) & 3);   // same key for srB+16
  const size_t gAoff  = (size_t)(bm + srA) * K + ssA * 8;
  const size_t gBoff0 = (size_t)(bn + srB) * K + ssB * 8;
  const size_t gBoff1 = gBoff0 + (size_t)16 * K;

  // fragment read offsets within a buffer (elements, swizzled)
  const int aoff = (wm * 64 + lr) * 32 + ((kg ^ sw) << 3);
  const int boff = (wn * 64 + lr) * 32 + ((kg ^ sw) << 3);

  const int nt = K >> 5;   // 24

#define STAGE(ts_) do {                                                    \
    bf16* lb_ = lds + ((ts_) & 1) * 12288;                                 \
    const size_t ko_ = (size_t)(ts_) * 32;                                 \
    gload16(A  + gAoff  + ko_, lb_ + wave * 512);                          \
    gload16(Bt + gBoff0 + ko_, lb_ + 4096 + wave * 1024);                  \
    gload16(Bt + gBoff1 + ko_, lb_ + 4096 + wave * 1024 + 512);            \
  } while (0)

  f32x4 acc[4][4] = {};

  STAGE(0);
  asm volatile("s_waitcnt vmcnt(0)" ::: "memory");
  __builtin_amdgcn_s_barrier();
  memfence();

  for (int t = 0; t < nt; ++t) {
    if (t + 1 < nt) STAGE(t + 1);   // issue prefetch BEFORE ds_read/MFMA

    const bf16* lA = lds + (t & 1) * 12288;
    const bf16* lB = lA + 4096;

    bf16x8 bfr[4], afr[4];
#pragma unroll
    for (int j = 0; j < 4; j++) bfr[j] = *(const bf16x8*)(lB + boff + j * 512);
#pragma unroll
    for (int i = 0; i < 4; i++) afr[i] = *(const bf16x8*)(lA + aoff + i * 512);

    __builtin_amdgcn_s_setprio(1);
#pragma unroll
    for (int i = 0; i < 4; i++)
#pragma unroll
      for (int j = 0; j < 4; j++)
        acc[i][j] = __builtin_amdgcn_mfma_f32_16x16x32_bf16(afr[i], bfr[j], acc[i][j], 0, 0, 0);
    __builtin_amdgcn_s_setprio(0);

    asm volatile("s_waitcnt vmcnt(0)" ::: "memory");  // tile t+1 landed
    __builtin_amdgcn_s_barrier();
    memfence();
  }
#undef STAGE

  // ---- coalesced epilogue (4 chunks of 32 rows via LDS [32][264]) ----
  {
    float* T = (float*)lds;
    const int CS = 264;
#pragma unroll
    for (int c = 0; c < 4; ++c) {
      __syncthreads();                 // prev chunk consumed / staging LDS free
      if ((c >> 1) == wm) {
#pragma unroll
        for (int s = 0; s < 2; ++s) {
          const int il = 2 * (c & 1) + s;
#pragma unroll
          for (int j = 0; j < 4; ++j)
#pragma unroll
            for (int r = 0; r < 4; ++r)
              T[(s * 16 + kg * 4 + r) * CS + wn * 64 + j * 16 + lr] = acc[il][j][r];
        }
      }
      __syncthreads();                 // full lgkmcnt drain: writes visible
#pragma unroll
      for (int q = 0; q < 4; ++q) {
        const int idx = q * 512 + tid;
        const int row = idx >> 6;        // 0..31
        const int c4  = idx & 63;        // 0..63 float4 cols (256 cols)
        const float4 b4 = *(const float4*)&bias[bn + c4 * 4];
        float4 v = *(const float4*)&T[row * CS + c4 * 4];
        v.x += b4.x; v.y += b4.y; v.z += b4.z; v.w += b4.w;
        *(float4*)&C[(size_t)(bm + c * 32 + row) * N + bn + c4 * 4] = v;
      }
    }
  }
}

// ---------------- depthwise causal conv (D_CONV=4) + silu -------------------
__global__ void k_conv(const float* __restrict__ xz, const float* __restrict__ cw,
                       const float* __restrict__ cb, float* __restrict__ xa) {
  const int bl = blockIdx.x;
  const int l  = bl & (L_SEQ - 1);
  for (int d = threadIdx.x; d < DINNER; d += blockDim.x) {
    float acc = cb[d];
#pragma unroll
    for (int k = 0; k < 4; k++) {
      const int ll = l + k - 3;
      if (ll >= 0)
        acc = fmaf(xz[(size_t)(bl + k - 3) * (2 * DINNER) + d], cw[d * 4 + k], acc);
    }
    xa[(size_t)bl * DINNER + d] = acc / (1.f + __expf(-acc));
  }
}

// ---------------- x_proj (round-16): wave-dot, 2 cols per wave ---------------
// dbl(2048,80) = xa(2048,1536) @ w_x. One wave owns (r, c0, c0+1); lanes split
// K interleaved (k = j*64 + lane) -> ALL loads are 256B wave-coalesced.
// fp32 butterfly-shfl reduction (deterministic; reassociation ~1e-7 rel).
__global__ __launch_bounds__(256) void k_xproj(
    const float* __restrict__ xa, const float* __restrict__ wt,
    float* __restrict__ dbl) {
  const int gw   = blockIdx.x * 4 + (threadIdx.x >> 6);   // 0..81919
  const int lane = threadIdx.x & 63;
  const int r  = gw / 40;
  const int c0 = (gw % 40) * 2;
  const float* xr = xa + (size_t)r * DINNER + lane;
  const float* w0 = wt + (size_t)c0 * DINNER + lane;
  const float* w1 = w0 + DINNER;
  float a0 = 0.f, a1 = 0.f;
#pragma unroll
  for (int j = 0; j < DINNER / 64; j++) {      // 24 iterations
    const float xv = xr[j * 64];
    a0 = fmaf(xv, w0[j * 64], a0);
    a1 = fmaf(xv, w1[j * 64], a1);
  }
#pragma unroll
  for (int off = 32; off > 0; off >>= 1) {
    a0 += __shfl_xor(a0, off);
    a1 += __shfl_xor(a1, off);
  }
  if (lane == 0) {
    dbl[(size_t)r * 80 + c0]     = a0;
    dbl[(size_t)r * 80 + c0 + 1] = a1;
  }
}

// ---------------- dt_proj + softplus, 8 rows/block (w_dt L2 reuse x8) -------
__global__ __launch_bounds__(256) void k_dtproj(
    const float* __restrict__ dbl, const float* __restrict__ w,
    const float* __restrict__ bvec, float* __restrict__ dt) {
  const int r0 = blockIdx.x * 8;
  const int tid = threadIdx.x;
  __shared__ float ds[8][DTRANK];
  for (int i = tid; i < 8 * DTRANK; i += 256)
    ds[i / DTRANK][i % DTRANK] = dbl[(size_t)(r0 + i / DTRANK) * 80 + i % DTRANK];
  __syncthreads();
  for (int c = tid; c < DINNER; c += 256) {
    const float bvc = bvec[c];
    float acc[8];
#pragma unroll
    for (int j = 0; j < 8; j++) acc[j] = bvc;
    for (int k = 0; k < DTRANK; k++) {
      const float wv = w[(size_t)k * DINNER + c];
#pragma unroll
      for (int j = 0; j < 8; j++) acc[j] = fmaf(ds[j][k], wv, acc[j]);
    }
#pragma unroll
    for (int j = 0; j < 8; j++) {
      const float a = acc[j];
      dt[(size_t)(r0 + j) * DINNER + c] = (a > 20.f) ? a : log1pf(expf(a));
    }
  }
}

// ======================= chunk-parallel selective scan =======================
__global__ __launch_bounds__(256) void k_scan1(
    const float* __restrict__ dt, const float* __restrict__ dbl,
    const float* __restrict__ xa, const float* __restrict__ a_log,
    float* __restrict__ P, float* __restrict__ S) {
  const int tid = threadIdx.x;
  const int d = blockIdx.x * 256 + tid;
  const int c = blockIdx.y;
  const int b = blockIdx.z;
  __shared__ float sB[CLEN][DSTATE];
  {
    const int j = tid >> 4, n = tid & 15;
    sB[j][n] = dbl[(size_t)(b * L_SEQ + c * CLEN + j) * 80 + DTRANK + n];
  }
  __syncthreads();
  float a[16];
#pragma unroll
  for (int q = 0; q < 4; q++) {
    const float4 v = *(const float4*)&a_log[d * DSTATE + q * 4];
    a[q*4+0] = -expf(v.x); a[q*4+1] = -expf(v.y);
    a[q*4+2] = -expf(v.z); a[q*4+3] = -expf(v.w);
  }
  float h[16] = {}, p[16];
#pragma unroll
  for (int n = 0; n < 16; n++) p[n] = 1.f;
  const size_t rowb = (size_t)(b * L_SEQ + c * CLEN);
#pragma unroll 4
  for (int j = 0; j < CLEN; j++) {
    const size_t row = rowb + j;
    const float dtv = dt[row * DINNER + d];
    const float xav = xa[row * DINNER + d];
    const float du  = dtv * xav;
#pragma unroll
    for (int n = 0; n < 16; n++) {
      const float dA = __expf(dtv * a[n]);
      h[n] = fmaf(dA, h[n], du * sB[j][n]);
      p[n] *= dA;
    }
  }
  const size_t base = (((size_t)c * B_SZ + b) * DINNER + d) * DSTATE;
#pragma unroll
  for (int q = 0; q < 4; q++) {
    *(float4*)&P[base + q * 4] = make_float4(p[q*4], p[q*4+1], p[q*4+2], p[q*4+3]);
    *(float4*)&S[base + q * 4] = make_float4(h[q*4], h[q*4+1], h[q*4+2], h[q*4+3]);
  }
}

__global__ __launch_bounds__(256) void k_scan2(
    const float* __restrict__ P, const float* __restrict__ S,
    float* __restrict__ Hin) {
  const int gid = blockIdx.x * 256 + threadIdx.x;   // (b*DINNER+d)*16+n
  const int STRIDE = B_SZ * DINNER * DSTATE;        // 49152
  float h = 0.f;
#pragma unroll 4
  for (int c = 0; c < NCH; c++) {
    Hin[(size_t)c * STRIDE + gid] = h;
    h = fmaf(P[(size_t)c * STRIDE + gid], h, S[(size_t)c * STRIDE + gid]);
  }
}

// scan3: re-scan with true h0, fused epilogue, writes hi/lo bf16 split of
// ycmb directly (feeds out_proj A operand)
__global__ __launch_bounds__(256) void k_scan3(
    const float* __restrict__ dt, const float* __restrict__ dbl,
    const float* __restrict__ xa, const float* __restrict__ a_log,
    const float* __restrict__ dvec, const float* __restrict__ xz,
    const float* __restrict__ Hin, bf16* __restrict__ ych,
    bf16* __restrict__ ycl) {
  const int tid = threadIdx.x;
  const int d = blockIdx.x * 256 + tid;
  const int c = blockIdx.y;
  const int b = blockIdx.z;
  __shared__ float sB[CLEN][DSTATE];
  __shared__ float sC[CLEN][DSTATE];
  {
    const int j = tid >> 4, n = tid & 15;
    const size_t r80 = (size_t)(b * L_SEQ + c * CLEN + j) * 80;
    sB[j][n] = dbl[r80 + DTRANK + n];
    sC[j][n] = dbl[r80 + DTRANK + DSTATE + n];
  }
  __syncthreads();
  float a[16];
#pragma unroll
  for (int q = 0; q < 4; q++) {
    const float4 v = *(const float4*)&a_log[d * DSTATE + q * 4];
    a[q*4+0] = -expf(v.x); a[q*4+1] = -expf(v.y);
    a[q*4+2] = -expf(v.z); a[q*4+3] = -expf(v.w);
  }
  float h[16];
  const size_t base = (((size_t)c * B_SZ + b) * DINNER + d) * DSTATE;
#pragma unroll
  for (int q = 0; q < 4; q++) {
    const float4 v = *(const float4*)&Hin[base + q * 4];
    h[q*4+0] = v.x; h[q*4+1] = v.y; h[q*4+2] = v.z; h[q*4+3] = v.w;
  }
  const float Dv = dvec[d];
  const size_t rowb = (size_t)(b * L_SEQ + c * CLEN);
#pragma unroll 4
  for (int j = 0; j < CLEN; j++) {
    const size_t row = rowb + j;
    const float dtv = dt[row * DINNER + d];
    const float xav = xa[row * DINNER + d];
    const float du  = dtv * xav;
    float y = 0.f;
#pragma unroll
    for (int n = 0; n < 16; n++) {
      const float dA = __expf(dtv * a[n]);
      h[n] = fmaf(dA, h[n], du * sB[j][n]);
      y = fmaf(h[n], sC[j][n], y);
    }
    const float z  = xz[row * (2 * DINNER) + DINNER + d];
    const float sz = z / (1.f + __expf(-z));
    const float val = fmaf(xav, Dv, y) * sz;
    const bf16 hv = (bf16)val;
    ych[row * DINNER + d] = hv;
    ycl[row * DINNER + d] = (bf16)(val - (float)hv);
  }
}

// ============================================================================
extern "C" void kernel_launch(void* const* d_in, const int* in_sizes, int n_in,
                              void* d_out, int out_size, void* d_ws, size_t ws_size,
                              hipStream_t stream) {
  const int*   ids   = (const int*)d_in[0];
  const float* emb   = (const float*)d_in[1];
  const float* w_in  = (const float*)d_in[2];   // 768 x 3072
  const float* cw    = (const float*)d_in[3];   // 1536 x 4
  const float* cb    = (const float*)d_in[4];
  const float* w_x   = (const float*)d_in[5];   // 1536 x 80
  const float* w_dt  = (const float*)d_in[6];   // 48 x 1536
  const float* b_dt  = (const float*)d_in[7];
  const float* a_log = (const float*)d_in[8];   // 1536 x 16
  const float* dvec  = (const float*)d_in[9];
  const float* w_out = (const float*)d_in[10];  // 1536 x 768
  const float* w_lm  = (const float*)d_in[11];  // 768 x 32000
  const float* b_lm  = (const float*)d_in[12];
  float* out = (float*)d_out;

  char* ws = (char*)d_ws;
  size_t off = 0;
  auto alloc = [&](size_t bytes) {
    void* p = ws + off;
    off = (off + bytes + 255) & ~(size_t)255;
    return p;
  };
  float* xw    = (float*)alloc((size_t)BL * DMODEL * 4);   // hosts wxt (492 KB)
  float* xz    = (float*)alloc((size_t)BL * 2 * DINNER * 4);
  float* xa    = (float*)alloc((size_t)BL * DINNER * 4);
  float* dbl   = (float*)alloc((size_t)BL * 80 * 4);
  float* dt    = (float*)alloc((size_t)BL * DINNER * 4);
  float* ycmb  = (float*)alloc((size_t)BL * DINNER * 4);   // (spare)
  float* yo    = (float*)alloc((size_t)BL * DMODEL * 4);   // (spare)
  bf16* xwh    = (bf16*)alloc((size_t)BL * DMODEL * 2);
  bf16* xwl    = (bf16*)alloc((size_t)BL * DMODEL * 2);
  bf16* wtinh  = (bf16*)alloc((size_t)3072 * DMODEL * 2);
  bf16* wtinl  = (bf16*)alloc((size_t)3072 * DMODEL * 2);
  bf16* ych    = (bf16*)alloc((size_t)BL * DINNER * 2);
  bf16* ycl    = (bf16*)alloc((size_t)BL * DINNER * 2);
  bf16* wtoh   = (bf16*)alloc((size_t)DMODEL * DINNER * 2);
  bf16* wtol   = (bf16*)alloc((size_t)DMODEL * DINNER * 2);
  bf16* yob    = (bf16*)alloc((size_t)BL * DMODEL * 2);
  bf16* wtlm   = (bf16*)alloc((size_t)VOCAB * DMODEL * 2);
  (void)ycmb; (void)yo;
  if (off > ws_size) {
    fprintf(stderr, "kernel_launch: ws too small (need %zu, have %zu)\n", off, ws_size);
    return;
  }

  // Aliased scratch (dead-lifetime regions):
  //  P -> xwh+xwl (dead after in_proj GEMM); S -> ych+ycl (scan3 overwrites
  //  AFTER scan2 consumed S); Hin -> wtlm (consumed by scan3, then tconv_lm
  //  overwrites); wxt -> xw (region otherwise unused).
  float* Pbuf = (float*)xwh;
  float* Sbuf = (float*)ych;
  float* Hin  = (float*)wtlm;
  float* wxt  = xw;   // 80 x 1536 f32

  // 48 KB dynamic LDS for k_gemm8 (staging 2 x 24576 B; epilogue 33792 B)
  (void)hipFuncSetAttribute((const void*)k_gemm8,
                            hipFuncAttributeMaxDynamicSharedMemorySize, 49152);

  // 1. embed fused with hi/lo split; transpose w_x for wave-dot xproj
  k_embed<<<BL, DMODEL / 4, 0, stream>>>(ids, emb, xwh, xwl);
  k_txw<<<dim3(DINNER / 16, 80 / 16), 256, 0, stream>>>(w_x, wxt);
  // 2. transpose-convert in_proj weight (64x64 tiles)
  k_tconv<true><<<dim3(3072 / 64, DMODEL / 64), 256, 0, stream>>>(w_in, wtinh, wtinl, DMODEL, 3072);
  // 3. in_proj GEMM (split, fp32-exact-ish): xz = xw @ w_in
  k_gemm<true, false, false><<<dim3(3072 / 128, BL / 128), 256, 0, stream>>>(
      xwh, xwl, wtinh, wtinl, nullptr, xz, BL, 3072, DMODEL);
  // 4. conv + silu
  k_conv<<<BL, 256, 0, stream>>>(xz, cw, cb, xa);
  // 5. x_proj (fp32, wave-dot coalesced)
  k_xproj<<<(BL * 40) / 4, 256, 0, stream>>>(xa, wxt, dbl);
  // 6. dt_proj + softplus (fp32, 8 rows/block)
  k_dtproj<<<BL / 8, 256, 0, stream>>>(dbl, w_dt, b_dt, dt);
  // 7. chunk-parallel scan; scan3 writes split bf16 directly
  k_scan1<<<dim3(DINNER / 256, NCH, B_SZ), 256, 0, stream>>>(dt, dbl, xa, a_log, Pbuf, Sbuf);
  k_scan2<<<(B_SZ * DINNER * DSTATE) / 256, 256, 0, stream>>>(Pbuf, Sbuf, Hin);
  k_scan3<<<dim3(DINNER / 256, NCH, B_SZ), 256, 0, stream>>>(dt, dbl, xa, a_log, dvec, xz, Hin, ych, ycl);
  // 8. out_proj GEMM (split), bf16 output fused (yob)
  k_tconv<true><<<dim3(DMODEL / 64, DINNER / 64), 256, 0, stream>>>(w_out, wtoh, wtol, DINNER, DMODEL);
  k_gemm<true, false, true><<<dim3(DMODEL / 128, BL / 128), 256, 0, stream>>>(
      ych, ycl, wtoh, wtol, nullptr, (float*)yob, BL, DMODEL, DINNER);
  // 9. lm_head GEMM: 128x256 8-wave 2-buf, coalesced fp32 epilogue
  k_tconv<false><<<dim3(VOCAB / 64, DMODEL / 64), 256, 0, stream>>>(w_lm, wtlm, nullptr, DMODEL, VOCAB);
  {
    const int mb = BL / 128;                 // 16
    const int nb = VOCAB / 256;              // 125
    k_gemm8<<<mb * nb, 512, 49152, stream>>>(yob, wtlm, b_lm, out,
                                             BL, VOCAB, DMODEL, mb);
  }
}